// Round 6
// baseline (194.476 us; speedup 1.0000x reference)
//
#include <hip/hip_runtime.h>
#include <stdint.h>

// LinearAttention on MI355X — round 6: V eliminated algebraically.
//   Ksm = softmax_n(W_k·x);  G_b = Ksm_b · x_b^T  (512x256 per b)
//   U[h] = W_out_h · W_v_h^T (batch-independent, 256x256)
//   M_b[o][hd] = sum_c U[h][o][c]·G_b[hd][c];  N_b = M_b·W_q;  out = N_b·x_b + bias
//
// ws layout (bytes):
//   Kb   bf16 [8][512][4096]   @ 0          (33,554,432)
//   xbT  bf16 [8][4096][256]   @ 33554432   (16,777,216)
//   xbc  bf16 [8][256][4096]   @ 50331648   (16,777,216)
//   wkb  bf16 [512][256]       @ 67108864   (   262,144)
//   woutb bf16 [256][512]      @ 67371008   (   262,144)
//   wqT  bf16 [256][512]       @ 67633152   (   262,144)
//   wvT  bf16 [256][512]       @ 67895296   (   262,144)
//   U    bf16 [4][256][256]    @ 68157440   (   524,288)
//   Gp   f32  [4][8][512][256] @ 68681728   (16,777,216)
//   G    bf16 [8][512][256]    @ 85458944   ( 2,097,152)
//   Mb   bf16 [8][256][512]    @ 87556096   ( 2,097,152)
//   Nb   bf16 [8][256][256]    @ 89653248   ( 1,048,576)
// total 90,701,824 B

using frag8 = __attribute__((ext_vector_type(8))) short;   // 8 x bf16
using f32x4 = __attribute__((ext_vector_type(4))) float;

__device__ __forceinline__ float bf2f(unsigned short u) {
    union { unsigned int u; float f; } c;
    c.u = ((unsigned int)u) << 16;
    return c.f;
}
__device__ __forceinline__ unsigned short f2bf(float f) {
    union { float f; unsigned int u; } c; c.f = f;
    unsigned int u = c.u;
    return (unsigned short)((u + 0x7FFFu + ((u >> 16) & 1u)) >> 16);
}

__device__ __forceinline__ void gl_lds16(const void* g, void* l) {
    __builtin_amdgcn_global_load_lds(
        (const __attribute__((address_space(1))) unsigned int*)g,
        (__attribute__((address_space(3))) unsigned int*)l, 16, 0, 0);
}

// ------- k0_weights: wkb, woutb (bf16 copy), wqT, wvT (bf16 transpose) -----
__global__ __launch_bounds__(256) void k0_weights(
    const float* __restrict__ w_qkv, const float* __restrict__ w_out,
    unsigned short* __restrict__ wkb, unsigned short* __restrict__ woutb,
    unsigned short* __restrict__ wqT, unsigned short* __restrict__ wvT)
{
    __shared__ float T[64][65];
    const int blk = blockIdx.x;
    const int tid = threadIdx.x;
    if (blk < 128) {                 // wkb: w_qkv rows 512..1024 -> bf16
        const int idx = (blk * 256 + tid) * 4;
        float4 v = *(const float4*)(w_qkv + 512 * 256 + idx);
        ushort4 o;
        o.x = f2bf(v.x); o.y = f2bf(v.y); o.z = f2bf(v.z); o.w = f2bf(v.w);
        *(ushort4*)(wkb + idx) = o;
    } else if (blk < 256) {          // woutb: w_out -> bf16
        const int idx = ((blk - 128) * 256 + tid) * 4;
        float4 v = *(const float4*)(w_out + idx);
        ushort4 o;
        o.x = f2bf(v.x); o.y = f2bf(v.y); o.z = f2bf(v.z); o.w = f2bf(v.w);
        *(ushort4*)(woutb + idx) = o;
    } else {                         // transpose blocks
        const int t2 = blk - 256;    // 0..63 : first 32 wqT (rows 0..512), next 32 wvT (rows 1024..1536)
        const int which = t2 >> 5;   // 0 = wqT, 1 = wvT
        const int t = t2 & 31;       // 8 j-tiles x 4 c-tiles
        const int j0 = (t >> 2) * 64, c0 = (t & 3) * 64;
        const float* src = w_qkv + (which ? 1024 * 256 : 0);
        unsigned short* dst = which ? wvT : wqT;
        const int r = tid >> 4, cc = (tid & 15) * 4;
        #pragma unroll
        for (int p = 0; p < 4; ++p) {
            float4 v = *(const float4*)(src + (j0 + r + p * 16) * 256 + c0 + cc);
            T[r + p * 16][cc + 0] = v.x; T[r + p * 16][cc + 1] = v.y;
            T[r + p * 16][cc + 2] = v.z; T[r + p * 16][cc + 3] = v.w;
        }
        __syncthreads();
        const int c = tid >> 2, jj = (tid & 3) * 16;
        #pragma unroll
        for (int g = 0; g < 4; ++g) {
            ushort4 o;
            o.x = f2bf(T[jj + g * 4 + 0][c]);
            o.y = f2bf(T[jj + g * 4 + 1][c]);
            o.z = f2bf(T[jj + g * 4 + 2][c]);
            o.w = f2bf(T[jj + g * 4 + 3][c]);
            *(ushort4*)(dst + (c0 + c) * 512 + j0 + jj + g * 4) = o;
        }
    }
}

// ------ k0_xt: xbT[b][n][c] = bf16(x[b][c][n]);  xbc[b][c][n] = bf16(x) ----
__global__ __launch_bounds__(256) void k0_xt(
    const float* __restrict__ x, unsigned short* __restrict__ xbT,
    unsigned short* __restrict__ xbc)
{
    __shared__ float T[64][65];
    const int tid = threadIdx.x;
    const int n0 = blockIdx.x * 64, c0 = blockIdx.y * 64, b = blockIdx.z;
    const float* xb = x + (size_t)b * 1048576;
    const int cr = tid >> 4, nc = (tid & 15) * 4;
    #pragma unroll
    for (int p = 0; p < 4; ++p) {
        float4 v = *(const float4*)(xb + (size_t)(c0 + cr + p * 16) * 4096 + n0 + nc);
        T[cr + p * 16][nc + 0] = v.x; T[cr + p * 16][nc + 1] = v.y;
        T[cr + p * 16][nc + 2] = v.z; T[cr + p * 16][nc + 3] = v.w;
        ushort4 o;
        o.x = f2bf(v.x); o.y = f2bf(v.y); o.z = f2bf(v.z); o.w = f2bf(v.w);
        *(ushort4*)(xbc + (size_t)b * 1048576 + (size_t)(c0 + cr + p * 16) * 4096 + n0 + nc) = o;
    }
    __syncthreads();
    const int n = tid >> 2, cc = (tid & 3) * 16;
    unsigned short* dst = xbT + (size_t)b * 1048576 + (size_t)(n0 + n) * 256 + c0 + cc;
    #pragma unroll
    for (int g = 0; g < 4; ++g) {
        ushort4 o;
        o.x = f2bf(T[cc + g * 4 + 0][n]);
        o.y = f2bf(T[cc + g * 4 + 1][n]);
        o.z = f2bf(T[cc + g * 4 + 2][n]);
        o.w = f2bf(T[cc + g * 4 + 3][n]);
        *(ushort4*)(dst + g * 4) = o;
    }
}

// -------- MFMA gemm_bt: C[m][n] = sum_k A[m][k] * B[n][k]  (bf16 in) -------
// 128x128 block tile, BK=32, 4 waves (each 64x64), 16x16x32 bf16 MFMA.
// MODE 0: C bf16, z-strided (kU, k1, k5).
// MODE 1: C f32 + bias[row] (k6).
// MODE 3: kM — A=U[h], B=G[b] rows h*128.., C=Mb[b] cols h*128.., K=256.
// MODE 4: k3G split-K — k-slice = (bx>>1)*1024, n0=(bx&1)*128, C f32 partials.
template<int MODE>
__global__ __launch_bounds__(256) void mfma_bt(
    const unsigned short* __restrict__ A0, int lda,
    const unsigned short* __restrict__ B0, int ldb,
    void* __restrict__ C0, int ldc,
    const float* __restrict__ bias, int Kp,
    unsigned long long sAz, unsigned long long sBz, unsigned long long sCz)
{
    __shared__ unsigned short As[128 * 32];
    __shared__ unsigned short Bs[128 * 32];
    const int tid  = threadIdx.x;
    const int w    = tid >> 6, lane = tid & 63;
    const int quad = lane >> 4, l16 = lane & 15;
    const int wm = (w >> 1) * 64, wn = (w & 1) * 64;
    const int z = blockIdx.z;

    const unsigned short* A;
    const unsigned short* B;
    int ks, ke, m0, n0;
    if constexpr (MODE == 3) {
        m0 = blockIdx.y * 128; n0 = 0;
        ks = 0; ke = 256;
        A = A0 + (unsigned long long)(z & 3) * 65536ull + (unsigned long long)m0 * lda;
        B = B0 + (unsigned long long)(z >> 2) * 131072ull + (unsigned long long)(z & 3) * 32768ull;
    } else if constexpr (MODE == 4) {
        m0 = blockIdx.y * 128; n0 = (blockIdx.x & 1) * 128;
        ks = (blockIdx.x >> 1) * 1024; ke = ks + 1024;
        A = A0 + sAz * z + (unsigned long long)m0 * lda;
        B = B0 + sBz * z + (unsigned long long)n0 * ldb;
    } else {
        m0 = blockIdx.y * 128; n0 = blockIdx.x * 128;
        ks = 0; ke = Kp;
        A = A0 + sAz * z + (unsigned long long)m0 * lda;
        B = B0 + sBz * z + (unsigned long long)n0 * ldb;
    }

    // staging: 512 chunks of 16B per tile; wave w handles chunks [w*128, w*128+128)
    const int cA0 = w * 128 + lane;
    const int cA1 = cA0 + 64;
    const unsigned short* gA0 = A + (unsigned long long)(cA0 >> 2) * lda + (cA0 & 3) * 8;
    const unsigned short* gA1 = A + (unsigned long long)(cA1 >> 2) * lda + (cA1 & 3) * 8;
    const unsigned short* gB0 = B + (unsigned long long)(cA0 >> 2) * ldb + (cA0 & 3) * 8;
    const unsigned short* gB1 = B + (unsigned long long)(cA1 >> 2) * ldb + (cA1 & 3) * 8;
    unsigned short* lA0 = As + w * 1024;
    unsigned short* lA1 = As + w * 1024 + 512;
    unsigned short* lB0 = Bs + w * 1024;
    unsigned short* lB1 = Bs + w * 1024 + 512;

    f32x4 acc[4][4] = {};

    for (int k0 = ks; k0 < ke; k0 += 32) {
        gl_lds16(gA0 + k0, lA0);
        gl_lds16(gA1 + k0, lA1);
        gl_lds16(gB0 + k0, lB0);
        gl_lds16(gB1 + k0, lB1);
        __syncthreads();
        frag8 a[4], b[4];
        #pragma unroll
        for (int t = 0; t < 4; ++t) {
            a[t] = *(const frag8*)(As + (wm + t * 16 + l16) * 32 + quad * 8);
            b[t] = *(const frag8*)(Bs + (wn + t * 16 + l16) * 32 + quad * 8);
        }
        #pragma unroll
        for (int mt = 0; mt < 4; ++mt)
            #pragma unroll
            for (int nt = 0; nt < 4; ++nt)
                acc[mt][nt] = __builtin_amdgcn_mfma_f32_16x16x32_bf16(
                    a[mt], b[nt], acc[mt][nt], 0, 0, 0);
        __syncthreads();
    }

    // epilogue: C/D mapping col = lane&15, row = quad*4 + reg  [m91-verified]
    if constexpr (MODE == 0 || MODE == 3) {
        unsigned short* C;
        if constexpr (MODE == 0)
            C = (unsigned short*)C0 + sCz * z + (unsigned long long)m0 * ldc + n0;
        else
            C = (unsigned short*)C0 + (unsigned long long)(z >> 2) * 131072ull
              + (unsigned long long)(z & 3) * 128ull + (unsigned long long)m0 * ldc;
        #pragma unroll
        for (int mt = 0; mt < 4; ++mt) {
            const int row = wm + mt * 16 + quad * 4;
            #pragma unroll
            for (int nt = 0; nt < 4; ++nt) {
                const int col = wn + nt * 16 + l16;
                #pragma unroll
                for (int r = 0; r < 4; ++r)
                    C[(unsigned long long)(row + r) * ldc + col] = f2bf(acc[mt][nt][r]);
            }
        }
    } else if constexpr (MODE == 1) {
        float* C = (float*)C0 + sCz * z + (unsigned long long)m0 * ldc + n0;
        const float* bp = bias + m0;
        #pragma unroll
        for (int mt = 0; mt < 4; ++mt) {
            const int row = wm + mt * 16 + quad * 4;
            #pragma unroll
            for (int nt = 0; nt < 4; ++nt) {
                const int col = wn + nt * 16 + l16;
                #pragma unroll
                for (int r = 0; r < 4; ++r)
                    C[(unsigned long long)(row + r) * ldc + col] = acc[mt][nt][r] + bp[row + r];
            }
        }
    } else {  // MODE 4: f32 partials, slice stride 1048576
        float* C = (float*)C0 + (unsigned long long)(blockIdx.x >> 1) * 1048576ull
                 + sCz * z + (unsigned long long)m0 * ldc + n0;
        #pragma unroll
        for (int mt = 0; mt < 4; ++mt) {
            const int row = wm + mt * 16 + quad * 4;
            #pragma unroll
            for (int nt = 0; nt < 4; ++nt) {
                const int col = wn + nt * 16 + l16;
                #pragma unroll
                for (int r = 0; r < 4; ++r)
                    C[(unsigned long long)(row + r) * ldc + col] = acc[mt][nt][r];
            }
        }
    }
}

// --------------- k2: in-place softmax over n on Kb rows --------------------
__global__ __launch_bounds__(256) void k2_softmax(unsigned short* __restrict__ Kb)
{
    __shared__ float red[4];
    unsigned short* row = Kb + (size_t)blockIdx.x * 4096;
    const int tid = threadIdx.x;
    float v[16];
    #pragma unroll
    for (int g = 0; g < 4; ++g) {
        ushort4 u = *(const ushort4*)(row + g * 1024 + tid * 4);
        v[g * 4 + 0] = bf2f(u.x); v[g * 4 + 1] = bf2f(u.y);
        v[g * 4 + 2] = bf2f(u.z); v[g * 4 + 3] = bf2f(u.w);
    }
    float m = -1e30f;
    #pragma unroll
    for (int i = 0; i < 16; ++i) m = fmaxf(m, v[i]);
    #pragma unroll
    for (int off = 32; off > 0; off >>= 1) m = fmaxf(m, __shfl_down(m, off, 64));
    if ((tid & 63) == 0) red[tid >> 6] = m;
    __syncthreads();
    m = fmaxf(fmaxf(red[0], red[1]), fmaxf(red[2], red[3]));
    __syncthreads();
    float s = 0.f;
    #pragma unroll
    for (int i = 0; i < 16; ++i) { v[i] = __expf(v[i] - m); s += v[i]; }
    #pragma unroll
    for (int off = 32; off > 0; off >>= 1) s += __shfl_down(s, off, 64);
    if ((tid & 63) == 0) red[tid >> 6] = s;
    __syncthreads();
    s = red[0] + red[1] + red[2] + red[3];
    const float inv = 1.0f / s;
    #pragma unroll
    for (int g = 0; g < 4; ++g) {
        ushort4 u;
        u.x = f2bf(v[g * 4 + 0] * inv); u.y = f2bf(v[g * 4 + 1] * inv);
        u.z = f2bf(v[g * 4 + 2] * inv); u.w = f2bf(v[g * 4 + 3] * inv);
        *(ushort4*)(row + g * 1024 + tid * 4) = u;
    }
}

// ----------- k3_sum: G[i] = bf16( sum_s Gp[s][i] ), i < 1048576 ------------
__global__ __launch_bounds__(256) void k3_sum(
    const float* __restrict__ Gp, unsigned short* __restrict__ G)
{
    const int idx = (blockIdx.x * 256 + threadIdx.x) * 4;
    float4 s = make_float4(0.f, 0.f, 0.f, 0.f);
    #pragma unroll
    for (int sl = 0; sl < 4; ++sl) {
        float4 t = *(const float4*)(Gp + (size_t)sl * 1048576 + idx);
        s.x += t.x; s.y += t.y; s.z += t.z; s.w += t.w;
    }
    ushort4 o;
    o.x = f2bf(s.x); o.y = f2bf(s.y); o.z = f2bf(s.z); o.w = f2bf(s.w);
    *(ushort4*)(G + idx) = o;
}

extern "C" void kernel_launch(void* const* d_in, const int* in_sizes, int n_in,
                              void* d_out, int out_size, void* d_ws, size_t ws_size,
                              hipStream_t stream) {
    (void)in_sizes; (void)n_in; (void)out_size; (void)ws_size;
    const float* x     = (const float*)d_in[0];  // f32 [8,256,64,64]
    const float* w_qkv = (const float*)d_in[1];  // f32 [1536,256]
    const float* w_out = (const float*)d_in[2];  // f32 [256,512]
    const float* b_out = (const float*)d_in[3];  // f32 [256]
    float* out = (float*)d_out;                  // f32 [8,256,64,64]

    char* ws = (char*)d_ws;
    unsigned short* Kb    = (unsigned short*)ws;                 // 33,554,432
    unsigned short* xbT   = (unsigned short*)(ws + 33554432);    // 16,777,216
    unsigned short* xbc   = (unsigned short*)(ws + 50331648);    // 16,777,216
    unsigned short* wkb   = (unsigned short*)(ws + 67108864);    //    262,144
    unsigned short* woutb = (unsigned short*)(ws + 67371008);    //    262,144
    unsigned short* wqT   = (unsigned short*)(ws + 67633152);    //    262,144
    unsigned short* wvT   = (unsigned short*)(ws + 67895296);    //    262,144
    unsigned short* U     = (unsigned short*)(ws + 68157440);    //    524,288
    float*          Gp    = (float*)(ws + 68681728);             // 16,777,216
    unsigned short* G     = (unsigned short*)(ws + 85458944);    //  2,097,152
    unsigned short* Mb    = (unsigned short*)(ws + 87556096);    //  2,097,152
    unsigned short* Nb    = (unsigned short*)(ws + 89653248);    //  1,048,576

    k0_weights<<<dim3(320), 256, 0, stream>>>(w_qkv, w_out, wkb, woutb, wqT, wvT);
    // kU: U[h][o][c] = sum_e woutb[o][h*128+e] * wvT[c][h*128+e]
    mfma_bt<0><<<dim3(2, 2, 4), 256, 0, stream>>>(
        woutb, 512, wvT, 512, U, 256, nullptr, 128,
        128ull, 128ull, 65536ull);
    k0_xt<<<dim3(64, 4, 8), 256, 0, stream>>>(x, xbT, xbc);
    // k1: Kb[b][r][n] = sum_c wkb[r][c] * xbT[b][n][c]
    mfma_bt<0><<<dim3(32, 4, 8), 256, 0, stream>>>(
        wkb, 256, xbT, 256, Kb, 4096, nullptr, 256,
        0ull, 1048576ull, 2097152ull);
    k2_softmax<<<dim3(4096), 256, 0, stream>>>(Kb);
    // k3G: Gp[ks][b][hd][c] = sum_{n in slice} Ksm[b][hd][n] * xbc[b][c][n]
    mfma_bt<4><<<dim3(8, 4, 8), 256, 0, stream>>>(
        Kb, 4096, xbc, 4096, Gp, 256, nullptr, 0,
        2097152ull, 1048576ull, 131072ull);
    k3_sum<<<dim3(1024), 256, 0, stream>>>(Gp, G);
    // kM: Mb[b][o][h*128+d] = sum_c U[h][o][c] * G[b][h*128+d][c]
    mfma_bt<3><<<dim3(1, 2, 32), 256, 0, stream>>>(
        U, 256, G, 256, Mb, 512, nullptr, 256,
        0ull, 0ull, 0ull);
    // k5: Nb[b][o][c] = sum_j Mb[b][o][j] * wqT[c][j]
    mfma_bt<0><<<dim3(2, 2, 8), 256, 0, stream>>>(
        Mb, 512, wqT, 512, Nb, 256, nullptr, 512,
        131072ull, 0ull, 65536ull);
    // k6: out[b][o][n] = sum_c Nb[b][o][c] * xbT[b][n][c] + b_out[o]
    mfma_bt<1><<<dim3(32, 2, 8), 256, 0, stream>>>(
        Nb, 256, xbT, 256, out, 4096, b_out, 256,
        65536ull, 1048576ull, 1048576ull);
}